// Round 13
// baseline (195.097 us; speedup 1.0000x reference)
//
#include <hip/hip_runtime.h>
#include <stdint.h>

typedef unsigned short u16;
typedef unsigned int u32;
typedef __attribute__((ext_vector_type(8))) short short8;
typedef __attribute__((ext_vector_type(4))) float float4v;

#define Bb 4
#define Ss 256
#define Hh 768
#define NALL 64
#define MAGIC 0x1234ABCD

// Inputs/outputs are FP32 (reference dtype; established r7).
// r13: NO global barrier (r4/r9/r10/r12: any O(grid) agent-RMW chain ~60-90us).
// Producer-consumer flags: release-STORE MAGIC per producer block (distinct
// words, no RMW, 0xAA ws-poison == "not ready"), consumers poll with 80
// parallel threads. Deadlock-free: 192 consumers < 1024 resident slots.

__device__ __forceinline__ float b2f(u16 h) {
    u32 u = ((u32)h) << 16;
    float f;
    __builtin_memcpy(&f, &u, 4);
    return f;
}
__device__ __forceinline__ u16 f2b(float f) {
    u32 u;
    __builtin_memcpy(&u, &f, 4);
    u = (u + 0x7fffu + ((u >> 16) & 1u)) >> 16;  // RNE
    return (u16)u;
}
union pk8 { uint4 v; u16 e[8]; };
__device__ __forceinline__ uint4 cvt8(float4 f0, float4 f1) {
    pk8 r;
    r.e[0] = f2b(f0.x); r.e[1] = f2b(f0.y); r.e[2] = f2b(f0.z); r.e[3] = f2b(f0.w);
    r.e[4] = f2b(f1.x); r.e[5] = f2b(f1.y); r.e[6] = f2b(f1.z); r.e[7] = f2b(f1.w);
    return r.v;
}

// z in [0,768):     mid producers: Gt[bk][o][j] = sum_i h[b][j][i] basic[q][i][o]
// z in [768,1792):  coefC producers (one per (b,i))
// z in [1792,1984): out consumers (poll 16 mid + 64 coef flags)
__global__ __launch_bounds__(256, 4) void k_all(const float* __restrict__ h,
                                                const int* __restrict__ rels,
                                                const float* __restrict__ basic,
                                                const float* __restrict__ relw,
                                                const float* __restrict__ selfw,
                                                u16* __restrict__ coefC,
                                                u16* __restrict__ Gt,
                                                int* __restrict__ flags,
                                                float* __restrict__ out) {
    __shared__ __align__(16) u16 As[64 * 72];
    __shared__ __align__(16) u16 Bs[64 * 72];
    const int z = blockIdx.x;
    const int t = threadIdx.x;
    const int row = t >> 2, kk = (t & 3) * 16;
    const int w = t >> 6, l = t & 63, quad = l >> 4, l16 = l & 15;

    if (z < 768) {
        // ---- mid producer (r7-verified): A = h (m=j), B = basic scatter-transposed ----
        const int ot = z % 12, jt = (z / 12) % 4, bk = z / 48;
        const int b = bk >> 2, q = bk & 3;
        const float* aB = h + ((size_t)b * Ss + jt * 64 + row) * Hh + kk;
        const float* bp = basic + ((size_t)q * Hh + row) * Hh + ot * 64 + kk;  // rows i, cols o

        float4v acc[4];
#pragma unroll
        for (int c = 0; c < 4; ++c) acc[c] = (float4v){0.f, 0.f, 0.f, 0.f};
        float4 a0 = *(const float4*)aB, a1 = *(const float4*)(aB + 4);
        float4 a2 = *(const float4*)(aB + 8), a3 = *(const float4*)(aB + 12);
        float4 b0 = *(const float4*)bp, b1 = *(const float4*)(bp + 4);
        float4 b2 = *(const float4*)(bp + 8), b3 = *(const float4*)(bp + 12);

        for (int s = 0; s < 12; ++s) {
            __syncthreads();
            *(uint4*)(&As[row * 72 + kk]) = cvt8(a0, a1);
            *(uint4*)(&As[row * 72 + kk + 8]) = cvt8(a2, a3);
            {   // scatter: Bs[o_local][i_local]; banks (4(kk+m)+row/2)%32 -> 2-way, free
                pk8 t0, t1;
                t0.v = cvt8(b0, b1);
                t1.v = cvt8(b2, b3);
#pragma unroll
                for (int m = 0; m < 8; ++m) Bs[(kk + m) * 72 + row] = t0.e[m];
#pragma unroll
                for (int m = 0; m < 8; ++m) Bs[(kk + 8 + m) * 72 + row] = t1.e[m];
            }
            __syncthreads();
            if (s + 1 < 12) {
                const float* ap = aB + (s + 1) * 64;
                const float* bq = bp + (size_t)(s + 1) * 64 * Hh;
                a0 = *(const float4*)ap;      a1 = *(const float4*)(ap + 4);
                a2 = *(const float4*)(ap + 8); a3 = *(const float4*)(ap + 12);
                b0 = *(const float4*)bq;      b1 = *(const float4*)(bq + 4);
                b2 = *(const float4*)(bq + 8); b3 = *(const float4*)(bq + 12);
            }
#pragma unroll
            for (int k2 = 0; k2 < 64; k2 += 32) {
                const short8 af = *(const short8*)(&As[(16 * w + l16) * 72 + k2 + quad * 8]);
#pragma unroll
                for (int c = 0; c < 4; ++c) {
                    const short8 bfr = *(const short8*)(&Bs[(16 * c + l16) * 72 + k2 + quad * 8]);
                    acc[c] = __builtin_amdgcn_mfma_f32_16x16x32_bf16(af, bfr, acc[c], 0, 0, 0);
                }
            }
        }
        // transposed epilogue through LDS: Gt[o][j]  (r7-verified)
        __syncthreads();
#pragma unroll
        for (int c = 0; c < 4; ++c)
#pragma unroll
            for (int r = 0; r < 4; ++r)
                As[(16 * c + l16) * 72 + 16 * w + quad * 4 + r] = f2b(acc[c][r]);
        __syncthreads();
#pragma unroll
        for (int uu = 0; uu < 2; ++uu) {
            const int u = t + uu * 256;
            const int oo = u >> 3, ch = u & 7;
            *(uint4*)(&Gt[((size_t)bk * Hh + ot * 64 + oo) * Ss + jt * 64 + ch * 8]) =
                *(const uint4*)(&As[oo * 72 + ch * 8]);
        }
        __syncthreads();  // drain all lanes' global writes before publishing
        if (t == 0)
            __hip_atomic_store(&flags[z], MAGIC, __ATOMIC_RELEASE, __HIP_MEMORY_SCOPE_AGENT);
    } else if (z < 1792) {
        // ---- coefC producer: one block per (b,i) (r8-verified) ----
        float* srelw = (float*)As;
        u32* hist = (u32*)Bs;
        const int r = z - 768;
        const int i = r & 255, b = r >> 8;
        srelw[t] = relw[t];
        if (t < NALL) hist[t] = 0u;
        __syncthreads();
        const int rfw = rels[(b * Ss + i) * Ss + t];
        const int rcl = rels[(b * Ss + t) * Ss + i];
        if (rfw > 0) atomicAdd(&hist[rfw], 1u);
        if (rcl > 0) atomicAdd(&hist[rcl + 32], 1u);
        __syncthreads();
        float c0 = 0.f, c1 = 0.f, c2 = 0.f, c3 = 0.f;
        if (rfw > 0) {
            const float inv = 1.0f / (float)hist[rfw];
            c0 += srelw[rfw * 4 + 0] * inv; c1 += srelw[rfw * 4 + 1] * inv;
            c2 += srelw[rfw * 4 + 2] * inv; c3 += srelw[rfw * 4 + 3] * inv;
        }
        if (rcl > 0) {
            const int rr = rcl + 32;
            const float inv = 1.0f / (float)hist[rr];
            c0 += srelw[rr * 4 + 0] * inv; c1 += srelw[rr * 4 + 1] * inv;
            c2 += srelw[rr * 4 + 2] * inv; c3 += srelw[rr * 4 + 3] * inv;
        }
        const size_t base = ((size_t)(b * 4) * Ss + i) * Ss + t;
        coefC[base] = f2b(c0);
        coefC[base + (size_t)Ss * Ss] = f2b(c1);
        coefC[base + (size_t)2 * Ss * Ss] = f2b(c2);
        coefC[base + (size_t)3 * Ss * Ss] = f2b(c3);
        __syncthreads();
        if (t == 0)
            __hip_atomic_store(&flags[z], MAGIC, __ATOMIC_RELEASE, __HIP_MEMORY_SCOPE_AGENT);
    } else {
        // ---- out consumer: out = coefC@Gt (K=1024) + h@selfw^T (K=768) ----
        const int idx = z - 1792;
        const int ot = idx % 12, it = (idx / 12) % 4, b = idx / 48;

        // parallel-thread flag wait: 16 mid + 64 coef flags, one per thread
        if (t < 80) {
            int zf;
            if (t < 16) {
                const int q = t >> 2, jt = t & 3;
                zf = ot + 12 * jt + 48 * (4 * b + q);
            } else {
                zf = 768 + b * 256 + it * 64 + (t - 16);
            }
            while (__hip_atomic_load(&flags[zf], __ATOMIC_RELAXED, __HIP_MEMORY_SCOPE_AGENT) != MAGIC)
                __builtin_amdgcn_s_sleep(16);
        }
        __syncthreads();
        if (t == 0) __builtin_amdgcn_fence(__ATOMIC_ACQUIRE, "agent");
        __syncthreads();

        uint4 ua0, ua1, ub0, ub1;
        float4 fa0, fa1, fa2, fa3, fb0, fb1, fb2, fb3;
        bool af32 = false, bf32 = false;
        auto loadA = [&](int s) {
            if (s < 16) {
                const u16* p = coefC + ((size_t)(b * 4 + (s >> 2)) * Ss + it * 64 + row) * Ss + (s & 3) * 64 + kk;
                ua0 = *(const uint4*)p; ua1 = *(const uint4*)(p + 8); af32 = false;
            } else {
                const float* p = h + ((size_t)b * Ss + it * 64 + row) * Hh + (s - 16) * 64 + kk;
                fa0 = *(const float4*)p;      fa1 = *(const float4*)(p + 4);
                fa2 = *(const float4*)(p + 8); fa3 = *(const float4*)(p + 12); af32 = true;
            }
        };
        auto loadB = [&](int s) {
            if (s < 16) {
                const u16* p = Gt + ((size_t)(b * 4 + (s >> 2)) * Hh + ot * 64 + row) * Ss + (s & 3) * 64 + kk;
                ub0 = *(const uint4*)p; ub1 = *(const uint4*)(p + 8); bf32 = false;
            } else {
                const float* p = selfw + (size_t)(ot * 64 + row) * Hh + (s - 16) * 64 + kk;
                fb0 = *(const float4*)p;      fb1 = *(const float4*)(p + 4);
                fb2 = *(const float4*)(p + 8); fb3 = *(const float4*)(p + 12); bf32 = true;
            }
        };
        float4v acc[4];
#pragma unroll
        for (int c = 0; c < 4; ++c) acc[c] = (float4v){0.f, 0.f, 0.f, 0.f};
        loadA(0); loadB(0);
        for (int s = 0; s < 28; ++s) {
            __syncthreads();
            if (af32) {
                *(uint4*)(&As[row * 72 + kk]) = cvt8(fa0, fa1);
                *(uint4*)(&As[row * 72 + kk + 8]) = cvt8(fa2, fa3);
            } else {
                *(uint4*)(&As[row * 72 + kk]) = ua0;
                *(uint4*)(&As[row * 72 + kk + 8]) = ua1;
            }
            if (bf32) {
                *(uint4*)(&Bs[row * 72 + kk]) = cvt8(fb0, fb1);
                *(uint4*)(&Bs[row * 72 + kk + 8]) = cvt8(fb2, fb3);
            } else {
                *(uint4*)(&Bs[row * 72 + kk]) = ub0;
                *(uint4*)(&Bs[row * 72 + kk + 8]) = ub1;
            }
            __syncthreads();
            if (s + 1 < 28) { loadA(s + 1); loadB(s + 1); }
#pragma unroll
            for (int k2 = 0; k2 < 64; k2 += 32) {
                const short8 af = *(const short8*)(&As[(16 * w + l16) * 72 + k2 + quad * 8]);
#pragma unroll
                for (int c = 0; c < 4; ++c) {
                    const short8 bfr = *(const short8*)(&Bs[(16 * c + l16) * 72 + k2 + quad * 8]);
                    acc[c] = __builtin_amdgcn_mfma_f32_16x16x32_bf16(af, bfr, acc[c], 0, 0, 0);
                }
            }
        }
#pragma unroll
        for (int c = 0; c < 4; ++c)
#pragma unroll
            for (int r = 0; r < 4; ++r) {
                const int il = 16 * w + quad * 4 + r;
                const int ol = 16 * c + l16;
                out[((size_t)b * Ss + it * 64 + il) * Hh + ot * 64 + ol] = acc[c][r];
            }
    }
}

extern "C" void kernel_launch(void* const* d_in, const int* in_sizes, int n_in,
                              void* d_out, int out_size, void* d_ws, size_t ws_size,
                              hipStream_t stream) {
    const float* h = (const float*)d_in[0];       // [4,256,768] fp32
    const int* rels = (const int*)d_in[1];        // [4,256,256] i32
    const float* basic = (const float*)d_in[2];   // [4,768,768] fp32
    const float* relw = (const float*)d_in[3];    // [64,4] fp32
    const float* selfw = (const float*)d_in[4];   // [768,768] fp32 (out,in)
    float* out = (float*)d_out;                   // [4,256,768] fp32

    // ws layout (u16 elems, 16B-aligned)
    u16* coefC = (u16*)d_ws;                           // 1,048,576
    u16* Gt = coefC + (size_t)Bb * 4 * Ss * Ss;        // 3,145,728  [bk][o][j]
    int* flags = (int*)(Gt + (size_t)Bb * 4 * Hh * Ss);  // 1792 ints

    k_all<<<1984, 256, 0, stream>>>(h, rels, basic, relw, selfw, coefC, Gt, flags, out);
}